// Round 21
// baseline (74.613 us; speedup 1.0000x reference)
//
#include <hip/hip_runtime.h>
#include <hip/hip_bf16.h>
#include <cstddef>
#include <cstdint>

#define DM 512
#define DK 64
#define BB 4
#define S4 4096
#define NR (BB*S4)      // 16384 rows
#define KVB 64
#define QBLOCK 128      // 4 waves x 32 q-rows
#define LP 72           // attn LDS row pitch in ushorts

typedef float   f32x16 __attribute__((ext_vector_type(16)));
typedef short   bf16x8 __attribute__((ext_vector_type(8)));

// Q pre-scale: 1/sqrt(64) * log2(e)  (softmax runs in exp2 domain)
#define QSCALE 0.18033688011112042f

__device__ __forceinline__ ushort bf16bits(float f) {
    __hip_bfloat16 h = __float2bfloat16(f);
    return *reinterpret_cast<ushort*>(&h);
}

// packed bf16 convert: low16 = bf16(a), high16 = bf16(b)   (RNE, 1 inst)
__device__ __forceinline__ uint32_t cvtpk(float a, float b) {
    uint32_t d;
    asm("v_cvt_pk_bf16_f32 %0, %1, %2" : "=v"(d) : "v"(a), "v"(b));
    return d;
}

// v_permlane32_swap_b32 a, b : a.hi-lanes <-> b.lo-lanes
__device__ __forceinline__ void permswap(uint32_t& a, uint32_t& b) {
    asm("v_permlane32_swap_b32 %0, %1" : "+v"(a), "+v"(b));
}

// ---------------- W prep: fragment-major hi/lo bf16 ----------------
__global__ __launch_bounds__(256) void prep_w(
    const float* __restrict__ wq, const float* __restrict__ wk,
    const float* __restrict__ wv,
    ushort* __restrict__ Wfh, ushort* __restrict__ Wfl)
{
    const int id = blockIdx.x * 256 + threadIdx.x;   // 98304 total
    const int c  = id >> 9, k = id & 511;
    const float* src = (c < 64) ? wq : (c < 128) ? wk : wv;
    const float wval = src[k * DK + (c & 63)];
    const ushort h  = bf16bits(wval);
    __hip_bfloat16 hh = *reinterpret_cast<const __hip_bfloat16*>(&h);
    const ushort l  = bf16bits(wval - __bfloat162float(hh));
    const int ko = k >> 6, ks = (k >> 4) & 3, kh = (k >> 3) & 1, e = k & 7;
    const size_t idx = ((size_t)((ko * 4 + ks) * 2 + kh) * 192 + c) * 8 + e;
    Wfh[idx] = h;
    Wfl[idx] = l;
}

// ---------------- QKV projection via MFMA — BARRIER-FREE (r16 proven) ----------------
__global__ __launch_bounds__(256, 3) void qkv_mfma(
    const float* __restrict__ x,
    const ushort* __restrict__ Wfh, const ushort* __restrict__ Wfl,
    const float* __restrict__ bq, const float* __restrict__ bk,
    const float* __restrict__ bv,
    ushort* __restrict__ Qb, ushort* __restrict__ Kb, ushort* __restrict__ Vt)
{
    __shared__ ushort Xw[4][2][32 * 72];   // per-wave double buffer, 36 KB

    const int tid  = threadIdx.x;
    const int w    = tid >> 6;
    const int lane = tid & 63;
    const int hi   = lane >> 5;       // k-half selector
    const int q5   = lane & 31;
    const int wr   = w >> 1, wc = w & 1;
    const size_t row0 = (size_t)blockIdx.x * 64;
    const int cidx = blockIdx.y * 2 + wc;   // global col-tile 0..5
    const int lrow = lane >> 4;       // 0..3 : row within 4-row burst
    const int lcol = lane & 15;       // 0..15: fp32-quad within row

    float4 xr[8];
    uint2  cw[8];

    auto gx = [&](int ko) {
        #pragma unroll
        for (int i = 0; i < 8; ++i) {
            const int r = wr * 32 + i * 4 + lrow;
            xr[i] = *(const float4*)&x[(row0 + r) * DM + ko * 64 + lcol * 4];
        }
    };
    auto cvt_all = [&]() {
        #pragma unroll
        for (int i = 0; i < 8; ++i)
            cw[i] = (uint2){cvtpk(xr[i].x, xr[i].y), cvtpk(xr[i].z, xr[i].w)};
    };
    auto wstage = [&](int buf) {
        ushort* base = &Xw[w][buf][0];
        #pragma unroll
        for (int i = 0; i < 8; ++i) {
            const int r = i * 4 + lrow;               // local row 0..31
            *reinterpret_cast<uint2*>(&base[r * 72 + lcol * 4]) = cw[i];
        }
    };

    f32x16 acc = {};

    gx(0); cvt_all(); wstage(0);
    gx(1);

    for (int ko = 0; ko < 8; ++ko) {
        const int cur = ko & 1;
        if (ko < 7) { cvt_all(); wstage(cur ^ 1); }   // cvt+write next tile
        if (ko < 6) gx(ko + 2);                       // issue loads 2 ahead

        const ushort* Xc = &Xw[w][cur][0];
        #pragma unroll
        for (int ks = 0; ks < 4; ++ks) {
            const bf16x8 ah = *reinterpret_cast<const bf16x8*>(
                &Xc[q5 * 72 + ks * 16 + hi * 8]);
            const int seg = (ko * 4 + ks) * 2 + hi;
            const size_t wb = ((size_t)seg * 192 + cidx * 32 + q5) * 8;
            const bf16x8 bh = *reinterpret_cast<const bf16x8*>(Wfh + wb);
            const bf16x8 bl = *reinterpret_cast<const bf16x8*>(Wfl + wb);
            acc = __builtin_amdgcn_mfma_f32_32x32x16_bf16(ah, bh, acc, 0, 0, 0);
            acc = __builtin_amdgcn_mfma_f32_32x32x16_bf16(ah, bl, acc, 0, 0, 0);
        }
    }

    const int mi = cidx >> 1, half = cidx & 1;
    const float* bp[3] = {bq, bk, bv};
    const float bias = bp[mi][half * 32 + q5];

    if (blockIdx.y == 2) {
        // ---- V path: in-block transpose via LDS, store Vt[b][dv][s] ----
        __syncthreads();      // all waves done with staging LDS (epilogue only)
        ushort* vt = &Xw[0][0][0];     // 64 x 64, pitch 72
        #pragma unroll
        for (int r = 0; r < 16; ++r) {
            const int rr = (r & 3) + 8 * (r >> 2) + 4 * hi;   // s_local
            vt[(half * 32 + q5) * 72 + wr * 32 + rr] = bf16bits(acc[r] + bias);
        }
        __syncthreads();
        const int dv = tid >> 2, sc = tid & 3;
        const int bb = (int)(row0 >> 12);          // row0 / S4
        const int sb = (int)(row0 & (S4 - 1));
        const ushort* src = vt + dv * 72 + sc * 16;
        uint4* dst = reinterpret_cast<uint4*>(
            Vt + ((size_t)bb * DK + dv) * S4 + sb + sc * 16);
        dst[0] = *reinterpret_cast<const uint4*>(src);
        dst[1] = *reinterpret_cast<const uint4*>(src + 8);
    } else {
        // ---- Q/K path: bias (+ QSCALE for Q), bf16 row-major store ----
        ushort* op = (mi == 0) ? Qb : Kb;
        #pragma unroll
        for (int r = 0; r < 16; ++r) {
            const int rr = (r & 3) + 8 * (r >> 2) + 4 * hi;
            const size_t grow = row0 + wr * 32 + rr;
            float v = acc[r] + bias;
            if (mi == 0) v *= QSCALE;
            op[grow * DK + half * 32 + q5] = bf16bits(v);
        }
    }
}

// ---------------- MFMA flash attention (no-max exact softmax) ----------------
// r16 structure (KVB=64, dbuf, stage-then-compute, 1 barrier/tile).
// ONE change: QK accumulation split into TWO INDEPENDENT 2-MFMA chains
// merged by f32 adds — shortens the serial MFMA latency on the per-sub
// critical path (~160 -> ~80 cy) at the cost of 16 VALU adds. This is a
// dataflow change (compiler must preserve the two-chain independence),
// distinct from the null/negative reorder attempts (r12/r18/r19).
__global__ __launch_bounds__(256, 4) void attn_mfma(
    const ushort* __restrict__ Qb, const ushort* __restrict__ Kb,
    const ushort* __restrict__ Vt,
    float* __restrict__ Opart, float* __restrict__ Lpart,
    float* __restrict__ out, int sigma)
{
    __shared__ ushort Ks[2][64 * LP];   // 2 x 9216 B
    __shared__ ushort Vs[2][64 * LP];

    const int tid  = threadIdx.x;
    const int w    = tid >> 6;
    const int lane = tid & 63;
    const int hi   = lane >> 5;
    const int q5   = lane & 31;
    const int b    = blockIdx.y, ci = blockIdx.z;
    const int klen = S4 / sigma, kv0 = ci * klen;
    const int qrow = blockIdx.x * QBLOCK + w * 32 + q5;

    const int c0 = tid, c1 = tid + 256;
    const int r0 = c0 >> 3, cc0 = c0 & 7;
    const int r1 = c1 >> 3, cc1 = c1 & 7;

    bf16x8 qf[4];
    {
        const ushort* qp = Qb + ((size_t)b * S4 + qrow) * DK;
        #pragma unroll
        for (int s = 0; s < 4; ++s)
            qf[s] = *reinterpret_cast<const bf16x8*>(qp + s * 16 + hi * 8);
    }

    bf16x8 onesv;
    #pragma unroll
    for (int i = 0; i < 8; ++i) onesv[i] = (short)0x3F80;

    f32x16 oacc0 = {}, oacc1 = {}, lacc = {};

    uint4 kreg0, kreg1, vreg0, vreg1;
    auto gload = [&](int t) {
        const ushort* gK = Kb + ((size_t)b * S4 + kv0 + t * KVB) * DK;
        const ushort* gV = Vt + (size_t)b * DK * S4 + (kv0 + t * KVB);
        kreg0 = *reinterpret_cast<const uint4*>(gK + r0 * DK + cc0 * 8);
        kreg1 = *reinterpret_cast<const uint4*>(gK + r1 * DK + cc1 * 8);
        vreg0 = *reinterpret_cast<const uint4*>(gV + (size_t)r0 * S4 + cc0 * 8);
        vreg1 = *reinterpret_cast<const uint4*>(gV + (size_t)r1 * S4 + cc1 * 8);
    };
    auto stage = [&](int buf) {
        *reinterpret_cast<uint4*>(&Ks[buf][r0 * LP + cc0 * 8]) = kreg0;
        *reinterpret_cast<uint4*>(&Ks[buf][r1 * LP + cc1 * 8]) = kreg1;
        *reinterpret_cast<uint4*>(&Vs[buf][r0 * LP + cc0 * 8]) = vreg0;
        *reinterpret_cast<uint4*>(&Vs[buf][r1 * LP + cc1 * 8]) = vreg1;
    };

    const int nt = klen / KVB;
    gload(0);
    stage(0);
    if (nt > 1) gload(1);
    __syncthreads();          // buf0 ready

    for (int t = 0; t < nt; ++t) {
        const int cur = t & 1;
        if (t + 1 < nt) {
            stage(cur ^ 1);               // write next buffer
            if (t + 2 < nt) gload(t + 2); // refill regs
        }
        const ushort* Kbuf = &Ks[cur][0];
        const ushort* Vbuf = &Vs[cur][0];

        #pragma unroll
        for (int sub = 0; sub < 2; ++sub) {
            const int kvr = sub * 32 + q5;
            bf16x8 kf[4];
            #pragma unroll
            for (int s = 0; s < 4; ++s)
                kf[s] = *reinterpret_cast<const bf16x8*>(
                    &Kbuf[kvr * LP + (2 * s + hi) * 8]);

            // two INDEPENDENT 2-MFMA chains, merged by f32 adds
            f32x16 sA = {}, sB = {};
            sA = __builtin_amdgcn_mfma_f32_32x32x16_bf16(kf[0], qf[0], sA, 0, 0, 0);
            sB = __builtin_amdgcn_mfma_f32_32x32x16_bf16(kf[2], qf[2], sB, 0, 0, 0);
            sA = __builtin_amdgcn_mfma_f32_32x32x16_bf16(kf[1], qf[1], sA, 0, 0, 0);
            sB = __builtin_amdgcn_mfma_f32_32x32x16_bf16(kf[3], qf[3], sB, 0, 0, 0);

            // p = exp2(sA+sB) directly — exact after O/L normalization
            float p[16];
            #pragma unroll
            for (int r = 0; r < 16; ++r) p[r] = exp2f(sA[r] + sB[r]);

            // ---- P -> bf16 PV A-fragments: 8 cvt_pk + 4 permlane32_swap ----
            uint32_t wd[8];
            #pragma unroll
            for (int g = 0; g < 4; ++g) {
                wd[2 * g]     = cvtpk(p[4 * g],     p[4 * g + 1]);
                wd[2 * g + 1] = cvtpk(p[4 * g + 2], p[4 * g + 3]);
            }
            permswap(wd[0], wd[2]);  permswap(wd[1], wd[3]);
            permswap(wd[4], wd[6]);  permswap(wd[5], wd[7]);
            union { uint32_t u[4]; bf16x8 v; } pa0, pa1;
            pa0.u[0] = wd[0]; pa0.u[1] = wd[1]; pa0.u[2] = wd[2]; pa0.u[3] = wd[3];
            pa1.u[0] = wd[4]; pa1.u[1] = wd[5]; pa1.u[2] = wd[6]; pa1.u[3] = wd[7];

            // lsum on matrix pipe: row-sum of the SAME bf16 P used by PV
            lacc = __builtin_amdgcn_mfma_f32_32x32x16_bf16(pa0.v, onesv, lacc, 0, 0, 0);
            lacc = __builtin_amdgcn_mfma_f32_32x32x16_bf16(pa1.v, onesv, lacc, 0, 0, 0);

            #pragma unroll
            for (int h = 0; h < 2; ++h) {
                const int dv = h * 32 + q5;
                #pragma unroll
                for (int tt = 0; tt < 2; ++tt) {
                    const bf16x8 vf = *reinterpret_cast<const bf16x8*>(
                        &Vbuf[dv * LP + (sub * 4 + tt * 2 + hi) * 8]);
                    if (h == 0)
                        oacc0 = __builtin_amdgcn_mfma_f32_32x32x16_bf16(
                            tt == 0 ? pa0.v : pa1.v, vf, oacc0, 0, 0, 0);
                    else
                        oacc1 = __builtin_amdgcn_mfma_f32_32x32x16_bf16(
                            tt == 0 ? pa0.v : pa1.v, vf, oacc1, 0, 0, 0);
                }
            }
        }
        __syncthreads();   // all reads of buf[cur] done
    }

    if (sigma == 1) {
        #pragma unroll
        for (int r = 0; r < 16; ++r) {
            const int qq = (r & 3) + 8 * (r >> 2) + 4 * hi;
            const float inv = 1.0f / lacc[r];
            const size_t row = (size_t)b * S4 + blockIdx.x * QBLOCK + w * 32 + qq;
            out[row * DK + q5]      = oacc0[r] * inv;
            out[row * DK + 32 + q5] = oacc1[r] * inv;
        }
    } else {
        if (q5 == 0) {
            #pragma unroll
            for (int r = 0; r < 16; ++r) {
                const int qq = (r & 3) + 8 * (r >> 2) + 4 * hi;
                const size_t row = (size_t)b * S4 + blockIdx.x * QBLOCK + w * 32 + qq;
                Lpart[(size_t)ci * NR + row] = lacc[r];
            }
        }
        #pragma unroll
        for (int r = 0; r < 16; ++r) {
            const int qq = (r & 3) + 8 * (r >> 2) + 4 * hi;
            const size_t row = (size_t)b * S4 + blockIdx.x * QBLOCK + w * 32 + qq;
            float* op = Opart + ((size_t)ci * NR + row) * DK;
            op[q5]      = oacc0[r];
            op[32 + q5] = oacc1[r];
        }
    }
}

// ---------------- merge KV-split partials: plain sums ----------------
__global__ __launch_bounds__(256) void attn_reduce(
    const float* __restrict__ Opart, const float* __restrict__ Lpart,
    float* __restrict__ out, int sigma)
{
    const int e4  = blockIdx.x * 256 + threadIdx.x;  // < NR*DK/4
    const int row = e4 >> 4;                         // 16 float4 per row
    const int d4  = e4 & 15;

    float L = 0.0f;
    float4 O = {0.0f, 0.0f, 0.0f, 0.0f};
    for (int i = 0; i < sigma; ++i) {
        L += Lpart[(size_t)i * NR + row];
        const float4 o = *reinterpret_cast<const float4*>(
            Opart + (((size_t)i * NR + row) << 6) + d4 * 4);
        O.x += o.x; O.y += o.y; O.z += o.z; O.w += o.w;
    }
    const float inv = 1.0f / L;
    float4 res = {O.x * inv, O.y * inv, O.z * inv, O.w * inv};
    *reinterpret_cast<float4*>(out + ((size_t)row << 6) + d4 * 4) = res;
}

extern "C" void kernel_launch(void* const* d_in, const int* in_sizes, int n_in,
                              void* d_out, int out_size, void* d_ws, size_t ws_size,
                              hipStream_t stream)
{
    const float* x  = (const float*)d_in[0];
    const float* wq = (const float*)d_in[1];
    const float* bq = (const float*)d_in[2];
    const float* wk = (const float*)d_in[3];
    const float* bk = (const float*)d_in[4];
    const float* wv = (const float*)d_in[5];
    const float* bv = (const float*)d_in[6];

    char* ws = (char*)d_ws;
    const size_t MB2  = (size_t)NR * DK * 2;     // 2 MB per bf16 matrix
    const size_t WTSZ = (size_t)192 * DM * 2;    // 192 KB per Wf matrix

    ushort* Qb  = (ushort*)(ws);
    ushort* Kb  = (ushort*)(ws + MB2);
    ushort* Vt  = (ushort*)(ws + 2 * MB2);
    ushort* Wfh = (ushort*)(ws + 3 * MB2);
    ushort* Wfl = (ushort*)(ws + 3 * MB2 + WTSZ);

    const size_t POFF = 3 * MB2 + 2 * WTSZ;

    int sigma = 1;
    const int cand[2] = {4, 2};
    for (int i = 0; i < 2; ++i) {
        const int s = cand[i];
        const size_t need = POFF + (size_t)s * ((size_t)NR * DK * 4 + (size_t)NR * 4);
        if (need <= ws_size) { sigma = s; break; }
    }

    float* Opart = (float*)(ws + POFF);
    float* Lpart = (float*)(ws + POFF + (size_t)sigma * NR * DK * 4);

    prep_w<<<384, 256, 0, stream>>>(wq, wk, wv, Wfh, Wfl);
    qkv_mfma<<<dim3(NR / 64, 3), 256, 0, stream>>>(x, Wfh, Wfl, bq, bk, bv,
                                                   Qb, Kb, Vt);

    dim3 grid(S4 / QBLOCK, BB, sigma);
    attn_mfma<<<grid, 256, 0, stream>>>(Qb, Kb, Vt, Opart, Lpart,
                                        (float*)d_out, sigma);

    if (sigma > 1)
        attn_reduce<<<(NR * DK) / 1024, 256, 0, stream>>>(Opart, Lpart,
                                                          (float*)d_out, sigma);
}

// Round 22
// 64.261 us; speedup vs baseline: 1.1611x; 1.1611x over previous
//
#include <hip/hip_runtime.h>
#include <hip/hip_bf16.h>
#include <cstddef>
#include <cstdint>

#define DM 512
#define DK 64
#define BB 4
#define S4 4096
#define NR (BB*S4)      // 16384 rows
#define KVB 64
#define QBLOCK 128      // 4 waves x 32 q-rows
#define LP 72           // attn LDS row pitch in ushorts

typedef float   f32x16 __attribute__((ext_vector_type(16)));
typedef short   bf16x8 __attribute__((ext_vector_type(8)));

// Q pre-scale: 1/sqrt(64) * log2(e)  (softmax runs in exp2 domain)
#define QSCALE 0.18033688011112042f

__device__ __forceinline__ ushort bf16bits(float f) {
    __hip_bfloat16 h = __float2bfloat16(f);
    return *reinterpret_cast<ushort*>(&h);
}

// packed bf16 convert: low16 = bf16(a), high16 = bf16(b)   (RNE, 1 inst)
__device__ __forceinline__ uint32_t cvtpk(float a, float b) {
    uint32_t d;
    asm("v_cvt_pk_bf16_f32 %0, %1, %2" : "=v"(d) : "v"(a), "v"(b));
    return d;
}

// v_permlane32_swap_b32 a, b : a.hi-lanes <-> b.lo-lanes
__device__ __forceinline__ void permswap(uint32_t& a, uint32_t& b) {
    asm("v_permlane32_swap_b32 %0, %1" : "+v"(a), "+v"(b));
}

// ---------------- W prep: fragment-major hi/lo bf16 ----------------
__global__ __launch_bounds__(256) void prep_w(
    const float* __restrict__ wq, const float* __restrict__ wk,
    const float* __restrict__ wv,
    ushort* __restrict__ Wfh, ushort* __restrict__ Wfl)
{
    const int id = blockIdx.x * 256 + threadIdx.x;   // 98304 total
    const int c  = id >> 9, k = id & 511;
    const float* src = (c < 64) ? wq : (c < 128) ? wk : wv;
    const float wval = src[k * DK + (c & 63)];
    const ushort h  = bf16bits(wval);
    __hip_bfloat16 hh = *reinterpret_cast<const __hip_bfloat16*>(&h);
    const ushort l  = bf16bits(wval - __bfloat162float(hh));
    const int ko = k >> 6, ks = (k >> 4) & 3, kh = (k >> 3) & 1, e = k & 7;
    const size_t idx = ((size_t)((ko * 4 + ks) * 2 + kh) * 192 + c) * 8 + e;
    Wfh[idx] = h;
    Wfl[idx] = l;
}

// ---------------- QKV projection via MFMA — BARRIER-FREE (r16 proven) ----------------
__global__ __launch_bounds__(256, 3) void qkv_mfma(
    const float* __restrict__ x,
    const ushort* __restrict__ Wfh, const ushort* __restrict__ Wfl,
    const float* __restrict__ bq, const float* __restrict__ bk,
    const float* __restrict__ bv,
    ushort* __restrict__ Qb, ushort* __restrict__ Kb, ushort* __restrict__ Vt)
{
    __shared__ ushort Xw[4][2][32 * 72];   // per-wave double buffer, 36 KB

    const int tid  = threadIdx.x;
    const int w    = tid >> 6;
    const int lane = tid & 63;
    const int hi   = lane >> 5;       // k-half selector
    const int q5   = lane & 31;
    const int wr   = w >> 1, wc = w & 1;
    const size_t row0 = (size_t)blockIdx.x * 64;
    const int cidx = blockIdx.y * 2 + wc;   // global col-tile 0..5
    const int lrow = lane >> 4;       // 0..3 : row within 4-row burst
    const int lcol = lane & 15;       // 0..15: fp32-quad within row

    float4 xr[8];
    uint2  cw[8];

    auto gx = [&](int ko) {
        #pragma unroll
        for (int i = 0; i < 8; ++i) {
            const int r = wr * 32 + i * 4 + lrow;
            xr[i] = *(const float4*)&x[(row0 + r) * DM + ko * 64 + lcol * 4];
        }
    };
    auto cvt_all = [&]() {
        #pragma unroll
        for (int i = 0; i < 8; ++i)
            cw[i] = (uint2){cvtpk(xr[i].x, xr[i].y), cvtpk(xr[i].z, xr[i].w)};
    };
    auto wstage = [&](int buf) {
        ushort* base = &Xw[w][buf][0];
        #pragma unroll
        for (int i = 0; i < 8; ++i) {
            const int r = i * 4 + lrow;               // local row 0..31
            *reinterpret_cast<uint2*>(&base[r * 72 + lcol * 4]) = cw[i];
        }
    };

    f32x16 acc = {};

    gx(0); cvt_all(); wstage(0);
    gx(1);

    for (int ko = 0; ko < 8; ++ko) {
        const int cur = ko & 1;
        if (ko < 7) { cvt_all(); wstage(cur ^ 1); }   // cvt+write next tile
        if (ko < 6) gx(ko + 2);                       // issue loads 2 ahead

        const ushort* Xc = &Xw[w][cur][0];
        #pragma unroll
        for (int ks = 0; ks < 4; ++ks) {
            const bf16x8 ah = *reinterpret_cast<const bf16x8*>(
                &Xc[q5 * 72 + ks * 16 + hi * 8]);
            const int seg = (ko * 4 + ks) * 2 + hi;
            const size_t wb = ((size_t)seg * 192 + cidx * 32 + q5) * 8;
            const bf16x8 bh = *reinterpret_cast<const bf16x8*>(Wfh + wb);
            const bf16x8 bl = *reinterpret_cast<const bf16x8*>(Wfl + wb);
            acc = __builtin_amdgcn_mfma_f32_32x32x16_bf16(ah, bh, acc, 0, 0, 0);
            acc = __builtin_amdgcn_mfma_f32_32x32x16_bf16(ah, bl, acc, 0, 0, 0);
        }
    }

    const int mi = cidx >> 1, half = cidx & 1;
    const float* bp[3] = {bq, bk, bv};
    const float bias = bp[mi][half * 32 + q5];

    if (blockIdx.y == 2) {
        // ---- V path: in-block transpose via LDS, store Vt[b][dv][s] ----
        __syncthreads();      // all waves done with staging LDS (epilogue only)
        ushort* vt = &Xw[0][0][0];     // 64 x 64, pitch 72
        #pragma unroll
        for (int r = 0; r < 16; ++r) {
            const int rr = (r & 3) + 8 * (r >> 2) + 4 * hi;   // s_local
            vt[(half * 32 + q5) * 72 + wr * 32 + rr] = bf16bits(acc[r] + bias);
        }
        __syncthreads();
        const int dv = tid >> 2, sc = tid & 3;
        const int bb = (int)(row0 >> 12);          // row0 / S4
        const int sb = (int)(row0 & (S4 - 1));
        const ushort* src = vt + dv * 72 + sc * 16;
        uint4* dst = reinterpret_cast<uint4*>(
            Vt + ((size_t)bb * DK + dv) * S4 + sb + sc * 16);
        dst[0] = *reinterpret_cast<const uint4*>(src);
        dst[1] = *reinterpret_cast<const uint4*>(src + 8);
    } else {
        // ---- Q/K path: bias (+ QSCALE for Q), bf16 row-major store ----
        ushort* op = (mi == 0) ? Qb : Kb;
        #pragma unroll
        for (int r = 0; r < 16; ++r) {
            const int rr = (r & 3) + 8 * (r >> 2) + 4 * hi;
            const size_t grow = row0 + wr * 32 + rr;
            float v = acc[r] + bias;
            if (mi == 0) v *= QSCALE;
            op[grow * DK + half * 32 + q5] = bf16bits(v);
        }
    }
}

// ---------------- MFMA flash attention (no-max exact softmax) ----------------
// r16 EXACT (session best, 64.5us, reproduced twice): KVB=64, dbuf,
// stage-then-compute, 1 barrier/tile, per-sub QK -> exp2 -> cvt_pk/permlane
// -> lacc-MFMA -> PV. Eleven levers verified null/negative on this
// structure: QK-hoist (r12), KVB=128 (r11), direct-L1 (r15), wave-private
// (r17), sigma=8 (r9), T14 (r18), T5 (r19), split-chain (r21), etc.
__global__ __launch_bounds__(256, 4) void attn_mfma(
    const ushort* __restrict__ Qb, const ushort* __restrict__ Kb,
    const ushort* __restrict__ Vt,
    float* __restrict__ Opart, float* __restrict__ Lpart,
    float* __restrict__ out, int sigma)
{
    __shared__ ushort Ks[2][64 * LP];   // 2 x 9216 B
    __shared__ ushort Vs[2][64 * LP];

    const int tid  = threadIdx.x;
    const int w    = tid >> 6;
    const int lane = tid & 63;
    const int hi   = lane >> 5;
    const int q5   = lane & 31;
    const int b    = blockIdx.y, ci = blockIdx.z;
    const int klen = S4 / sigma, kv0 = ci * klen;
    const int qrow = blockIdx.x * QBLOCK + w * 32 + q5;

    const int c0 = tid, c1 = tid + 256;
    const int r0 = c0 >> 3, cc0 = c0 & 7;
    const int r1 = c1 >> 3, cc1 = c1 & 7;

    bf16x8 qf[4];
    {
        const ushort* qp = Qb + ((size_t)b * S4 + qrow) * DK;
        #pragma unroll
        for (int s = 0; s < 4; ++s)
            qf[s] = *reinterpret_cast<const bf16x8*>(qp + s * 16 + hi * 8);
    }

    bf16x8 onesv;
    #pragma unroll
    for (int i = 0; i < 8; ++i) onesv[i] = (short)0x3F80;

    f32x16 oacc0 = {}, oacc1 = {}, lacc = {};

    uint4 kreg0, kreg1, vreg0, vreg1;
    auto gload = [&](int t) {
        const ushort* gK = Kb + ((size_t)b * S4 + kv0 + t * KVB) * DK;
        const ushort* gV = Vt + (size_t)b * DK * S4 + (kv0 + t * KVB);
        kreg0 = *reinterpret_cast<const uint4*>(gK + r0 * DK + cc0 * 8);
        kreg1 = *reinterpret_cast<const uint4*>(gK + r1 * DK + cc1 * 8);
        vreg0 = *reinterpret_cast<const uint4*>(gV + (size_t)r0 * S4 + cc0 * 8);
        vreg1 = *reinterpret_cast<const uint4*>(gV + (size_t)r1 * S4 + cc1 * 8);
    };
    auto stage = [&](int buf) {
        *reinterpret_cast<uint4*>(&Ks[buf][r0 * LP + cc0 * 8]) = kreg0;
        *reinterpret_cast<uint4*>(&Ks[buf][r1 * LP + cc1 * 8]) = kreg1;
        *reinterpret_cast<uint4*>(&Vs[buf][r0 * LP + cc0 * 8]) = vreg0;
        *reinterpret_cast<uint4*>(&Vs[buf][r1 * LP + cc1 * 8]) = vreg1;
    };

    const int nt = klen / KVB;
    gload(0);
    stage(0);
    if (nt > 1) gload(1);
    __syncthreads();          // buf0 ready

    for (int t = 0; t < nt; ++t) {
        const int cur = t & 1;
        if (t + 1 < nt) {
            stage(cur ^ 1);               // write next buffer
            if (t + 2 < nt) gload(t + 2); // refill regs
        }
        const ushort* Kbuf = &Ks[cur][0];
        const ushort* Vbuf = &Vs[cur][0];

        #pragma unroll
        for (int sub = 0; sub < 2; ++sub) {
            const int kvr = sub * 32 + q5;
            bf16x8 kf[4];
            #pragma unroll
            for (int s = 0; s < 4; ++s)
                kf[s] = *reinterpret_cast<const bf16x8*>(
                    &Kbuf[kvr * LP + (2 * s + hi) * 8]);
            f32x16 sacc = {};
            #pragma unroll
            for (int s = 0; s < 4; ++s)
                sacc = __builtin_amdgcn_mfma_f32_32x32x16_bf16(
                    kf[s], qf[s], sacc, 0, 0, 0);

            // p = exp2(s) directly — exact after O/L normalization
            float p[16];
            #pragma unroll
            for (int r = 0; r < 16; ++r) p[r] = exp2f(sacc[r]);

            // ---- P -> bf16 PV A-fragments: 8 cvt_pk + 4 permlane32_swap ----
            uint32_t wd[8];
            #pragma unroll
            for (int g = 0; g < 4; ++g) {
                wd[2 * g]     = cvtpk(p[4 * g],     p[4 * g + 1]);
                wd[2 * g + 1] = cvtpk(p[4 * g + 2], p[4 * g + 3]);
            }
            permswap(wd[0], wd[2]);  permswap(wd[1], wd[3]);
            permswap(wd[4], wd[6]);  permswap(wd[5], wd[7]);
            union { uint32_t u[4]; bf16x8 v; } pa0, pa1;
            pa0.u[0] = wd[0]; pa0.u[1] = wd[1]; pa0.u[2] = wd[2]; pa0.u[3] = wd[3];
            pa1.u[0] = wd[4]; pa1.u[1] = wd[5]; pa1.u[2] = wd[6]; pa1.u[3] = wd[7];

            // lsum on matrix pipe: row-sum of the SAME bf16 P used by PV
            lacc = __builtin_amdgcn_mfma_f32_32x32x16_bf16(pa0.v, onesv, lacc, 0, 0, 0);
            lacc = __builtin_amdgcn_mfma_f32_32x32x16_bf16(pa1.v, onesv, lacc, 0, 0, 0);

            #pragma unroll
            for (int h = 0; h < 2; ++h) {
                const int dv = h * 32 + q5;
                #pragma unroll
                for (int tt = 0; tt < 2; ++tt) {
                    const bf16x8 vf = *reinterpret_cast<const bf16x8*>(
                        &Vbuf[dv * LP + (sub * 4 + tt * 2 + hi) * 8]);
                    if (h == 0)
                        oacc0 = __builtin_amdgcn_mfma_f32_32x32x16_bf16(
                            tt == 0 ? pa0.v : pa1.v, vf, oacc0, 0, 0, 0);
                    else
                        oacc1 = __builtin_amdgcn_mfma_f32_32x32x16_bf16(
                            tt == 0 ? pa0.v : pa1.v, vf, oacc1, 0, 0, 0);
                }
            }
        }
        __syncthreads();   // all reads of buf[cur] done
    }

    if (sigma == 1) {
        #pragma unroll
        for (int r = 0; r < 16; ++r) {
            const int qq = (r & 3) + 8 * (r >> 2) + 4 * hi;
            const float inv = 1.0f / lacc[r];
            const size_t row = (size_t)b * S4 + blockIdx.x * QBLOCK + w * 32 + qq;
            out[row * DK + q5]      = oacc0[r] * inv;
            out[row * DK + 32 + q5] = oacc1[r] * inv;
        }
    } else {
        if (q5 == 0) {
            #pragma unroll
            for (int r = 0; r < 16; ++r) {
                const int qq = (r & 3) + 8 * (r >> 2) + 4 * hi;
                const size_t row = (size_t)b * S4 + blockIdx.x * QBLOCK + w * 32 + qq;
                Lpart[(size_t)ci * NR + row] = lacc[r];
            }
        }
        #pragma unroll
        for (int r = 0; r < 16; ++r) {
            const int qq = (r & 3) + 8 * (r >> 2) + 4 * hi;
            const size_t row = (size_t)b * S4 + blockIdx.x * QBLOCK + w * 32 + qq;
            float* op = Opart + ((size_t)ci * NR + row) * DK;
            op[q5]      = oacc0[r];
            op[32 + q5] = oacc1[r];
        }
    }
}

// ---------------- merge KV-split partials: plain sums ----------------
__global__ __launch_bounds__(256) void attn_reduce(
    const float* __restrict__ Opart, const float* __restrict__ Lpart,
    float* __restrict__ out, int sigma)
{
    const int e4  = blockIdx.x * 256 + threadIdx.x;  // < NR*DK/4
    const int row = e4 >> 4;                         // 16 float4 per row
    const int d4  = e4 & 15;

    float L = 0.0f;
    float4 O = {0.0f, 0.0f, 0.0f, 0.0f};
    for (int i = 0; i < sigma; ++i) {
        L += Lpart[(size_t)i * NR + row];
        const float4 o = *reinterpret_cast<const float4*>(
            Opart + (((size_t)i * NR + row) << 6) + d4 * 4);
        O.x += o.x; O.y += o.y; O.z += o.z; O.w += o.w;
    }
    const float inv = 1.0f / L;
    float4 res = {O.x * inv, O.y * inv, O.z * inv, O.w * inv};
    *reinterpret_cast<float4*>(out + ((size_t)row << 6) + d4 * 4) = res;
}

extern "C" void kernel_launch(void* const* d_in, const int* in_sizes, int n_in,
                              void* d_out, int out_size, void* d_ws, size_t ws_size,
                              hipStream_t stream)
{
    const float* x  = (const float*)d_in[0];
    const float* wq = (const float*)d_in[1];
    const float* bq = (const float*)d_in[2];
    const float* wk = (const float*)d_in[3];
    const float* bk = (const float*)d_in[4];
    const float* wv = (const float*)d_in[5];
    const float* bv = (const float*)d_in[6];

    char* ws = (char*)d_ws;
    const size_t MB2  = (size_t)NR * DK * 2;     // 2 MB per bf16 matrix
    const size_t WTSZ = (size_t)192 * DM * 2;    // 192 KB per Wf matrix

    ushort* Qb  = (ushort*)(ws);
    ushort* Kb  = (ushort*)(ws + MB2);
    ushort* Vt  = (ushort*)(ws + 2 * MB2);
    ushort* Wfh = (ushort*)(ws + 3 * MB2);
    ushort* Wfl = (ushort*)(ws + 3 * MB2 + WTSZ);

    const size_t POFF = 3 * MB2 + 2 * WTSZ;

    int sigma = 1;
    const int cand[2] = {4, 2};
    for (int i = 0; i < 2; ++i) {
        const int s = cand[i];
        const size_t need = POFF + (size_t)s * ((size_t)NR * DK * 4 + (size_t)NR * 4);
        if (need <= ws_size) { sigma = s; break; }
    }

    float* Opart = (float*)(ws + POFF);
    float* Lpart = (float*)(ws + POFF + (size_t)sigma * NR * DK * 4);

    prep_w<<<384, 256, 0, stream>>>(wq, wk, wv, Wfh, Wfl);
    qkv_mfma<<<dim3(NR / 64, 3), 256, 0, stream>>>(x, Wfh, Wfl, bq, bk, bv,
                                                   Qb, Kb, Vt);

    dim3 grid(S4 / QBLOCK, BB, sigma);
    attn_mfma<<<grid, 256, 0, stream>>>(Qb, Kb, Vt, Opart, Lpart,
                                        (float*)d_out, sigma);

    if (sigma > 1)
        attn_reduce<<<(NR * DK) / 1024, 256, 0, stream>>>(Opart, Lpart,
                                                          (float*)d_out, sigma);
}